// Round 10
// baseline (384.228 us; speedup 1.0000x reference)
//
#include <hip/hip_runtime.h>

#define N_NODES 50000
#define N_GRAPHS 512
#define N_EDGES 800000
#define NBKT 49   // ceil(50000/1024) coarse dst-buckets

typedef __attribute__((ext_vector_type(8))) short short8;
typedef __attribute__((ext_vector_type(8))) unsigned short ushort8;
typedef __attribute__((ext_vector_type(4))) float floatx4;
typedef __attribute__((ext_vector_type(2))) float floatx2;

__device__ __forceinline__ float bf2f(unsigned short u) {
    union { unsigned int i; float f; } c;
    c.i = ((unsigned int)u) << 16;
    return c.f;
}
__device__ __forceinline__ unsigned short f2bf(float f) {
    union { float f; unsigned int i; } c;
    c.f = f;
    unsigned int u = c.i;
    return (unsigned short)((u + 0x7fffu + ((u >> 16) & 1u)) >> 16);
}

// ---- fp8 e4m3fn encode (software RNE, clamp ±448, flush |v|<2^-6) ---------
// decode is HW v_cvt_pk_f32_fp8 (exact widening, OCP on gfx950).
__device__ __forceinline__ unsigned char ftofp8(float f) {
    union { float f; unsigned int u; } c; c.f = f;
    unsigned int s = (c.u >> 24) & 0x80u;
    float a = fabsf(f);
    if (a < 0x1p-6f) return (unsigned char)s;
    if (a > 448.f)   return (unsigned char)(s | 0x7E);
    unsigned int u = c.u & 0x7FFFFFFFu;
    unsigned int r = u + 0x7FFFFu + ((u >> 20) & 1u);
    return (unsigned char)(s | (((r >> 23) - 120u) << 3) | ((r >> 20) & 7u));
}

// HW decode of 8 packed fp8 (uint2) accumulated into acc[8]
__device__ __forceinline__ void f8acc(float* acc, uint2 v) {
    floatx2 a = __builtin_amdgcn_cvt_pk_f32_fp8(v.x, false);
    floatx2 b = __builtin_amdgcn_cvt_pk_f32_fp8(v.x, true);
    floatx2 c = __builtin_amdgcn_cvt_pk_f32_fp8(v.y, false);
    floatx2 d = __builtin_amdgcn_cvt_pk_f32_fp8(v.y, true);
    acc[0] += a[0]; acc[1] += a[1]; acc[2] += b[0]; acc[3] += b[1];
    acc[4] += c[0]; acc[5] += c[1]; acc[6] += d[0]; acc[7] += d[1];
}

// async 16B global -> LDS (lane-ordered destination: ldsbase + lane*16)
__device__ __forceinline__ void g2lds16(const unsigned short* g, void* lds) {
    __builtin_amdgcn_global_load_lds(
        (const __attribute__((address_space(1))) void*)g,
        (__attribute__((address_space(3))) void*)lds, 16, 0, 0);
}

// ------ fused prep: x->fp8 + W1-3->bf16 + deg histogram + sums zeroing -----
__global__ void conv_deg(const float* __restrict__ x, const float* __restrict__ W1,
                         const float* __restrict__ W2, const float* __restrict__ W3,
                         const int* __restrict__ dst,
                         unsigned char* __restrict__ xf8, unsigned short* __restrict__ o1,
                         unsigned short* __restrict__ o2, unsigned short* __restrict__ o3,
                         int* __restrict__ deg, float4* __restrict__ sums4) {
    int i = blockIdx.x * blockDim.x + threadIdx.x;
    if (i >= 2440960) {
        int j = i - 2440960;
        if (j < 32768) sums4[j] = make_float4(0.f, 0.f, 0.f, 0.f);
        return;
    }
    if (i >= 1640960) {
        int e = i - 1640960;
        atomicAdd(&deg[dst[e]], 1);
        return;
    }
    if (i < 1600000) {
        float4 v = ((const float4*)x)[i];
        uchar4 o;
        o.x = ftofp8(v.x); o.y = ftofp8(v.y); o.z = ftofp8(v.z); o.w = ftofp8(v.w);
        ((uchar4*)xf8)[i] = o;
        return;
    }
    int j = i - 1600000;
    const float* src; unsigned short* out; int base;
    if (j < 8192)       { src = W1; out = o1; base = j; }
    else if (j < 24576) { src = W2; out = o2; base = j - 8192; }
    else                { src = W3; out = o3; base = j - 24576; }
    float4 v = ((const float4*)src)[base];
    ushort4 o;
    o.x = f2bf(v.x); o.y = f2bf(v.y); o.z = f2bf(v.z); o.w = f2bf(v.w);
    ((ushort4*)out)[base] = o;
}

// ---------------- CSR scan chain (scan2 folded into scan3) -----------------
__global__ __launch_bounds__(1024) void scan1(const int* __restrict__ deg,
                                              int* __restrict__ rowptr,
                                              int* __restrict__ blocksum) {
    __shared__ int s[1024];
    int t = threadIdx.x;
    int i = blockIdx.x * 1024 + t;
    int v = (i < N_NODES) ? deg[i] : 0;
    s[t] = v;
    __syncthreads();
    for (int off = 1; off < 1024; off <<= 1) {
        int add = (t >= off) ? s[t - off] : 0;
        __syncthreads();
        s[t] += add;
        __syncthreads();
    }
    if (i < N_NODES) rowptr[i] = s[t] - v;  // exclusive within block
    if (t == 1023) blocksum[blockIdx.x] = s[t];
}

// redundant wave-scan of block sums, then apply; also emits per-bucket
// cursors (gcursor[b] = rowptr[1024b]) for the binned scatter.
__global__ __launch_bounds__(1024) void scan3(int* __restrict__ rowptr,
                                              const int* __restrict__ blocksum,
                                              int* __restrict__ cursor,
                                              int* __restrict__ gcursor) {
    __shared__ int bse[64];
    int t = threadIdx.x;
    if (t < 64) {
        const int NB = (N_NODES + 1023) / 1024;  // 49
        int orig = (t < NB) ? blocksum[t] : 0;
        int v = orig;
        for (int off = 1; off < 64; off <<= 1) {
            int u = __shfl_up(v, off, 64);
            if (t >= off) v += u;
        }
        bse[t] = v - orig;  // exclusive
    }
    __syncthreads();
    int i = blockIdx.x * 1024 + t;
    if (i < N_NODES) {
        int v = rowptr[i] + bse[i >> 10];
        rowptr[i] = v;
        cursor[i] = v;
        if ((i & 1023) == 0) gcursor[i >> 10] = v;
    }
    if (i == 0) rowptr[N_NODES] = N_EDGES;
}

// ---- binned CSR scatter, phase 1: LDS-binned staging write ----------------
// R9: flat scatter_csr had 16x write amplification (WRITE 52 MB for 3.2 MB
// of data: each 64B line written by 16 scattered threads). Phase 1 bins
// edges into 49 dst-buckets with block-contiguous staging chunks
// (amplification ~1.4x); phase 2 confines final scatter to one block per
// bucket so each csr line is written from a single XCD's L2.
__global__ __launch_bounds__(256) void bin_edges(const int* __restrict__ src,
                                                 const int* __restrict__ dst,
                                                 int* __restrict__ gcursor,
                                                 unsigned int* __restrict__ staging) {
    __shared__ int cnt[NBKT];
    __shared__ int base[NBKT];
    int t = threadIdx.x;
    if (t < NBKT) cnt[t] = 0;
    __syncthreads();
    int e0 = blockIdx.x * 2048;
    int d[8], s[8];
#pragma unroll
    for (int r = 0; r < 8; r++) {
        int e = e0 + r * 256 + t;
        if (e < N_EDGES) {
            d[r] = dst[e]; s[r] = src[e];
            atomicAdd(&cnt[d[r] >> 10], 1);
        } else d[r] = -1;
    }
    __syncthreads();
    if (t < NBKT) base[t] = atomicAdd(&gcursor[t], cnt[t]);
    __syncthreads();
#pragma unroll
    for (int r = 0; r < 8; r++) {
        if (d[r] >= 0) {
            int off = atomicAdd(&base[d[r] >> 10], 1);
            staging[off] = ((unsigned)d[r] << 16) | (unsigned)s[r];
        }
    }
}

// ---- binned CSR scatter, phase 2: per-bucket ordered scatter --------------
// one block per bucket; all writes land in the bucket's ~65 KB csr window.
__global__ __launch_bounds__(1024) void scatter_bkt(const unsigned int* __restrict__ staging,
                                                    const int* __restrict__ rowptr,
                                                    int* __restrict__ cursor,
                                                    unsigned short* __restrict__ csr) {
    int b = blockIdx.x;
    int lo = rowptr[b << 10];
    int nhi = (b + 1) << 10; if (nhi > N_NODES) nhi = N_NODES;
    int hi = rowptr[nhi];
    for (int p = lo + threadIdx.x; p < hi; p += 1024) {
        unsigned v = staging[p];
        int d = v >> 16;
        int pos = atomicAdd(&cursor[d], 1);
        csr[pos] = (unsigned short)(v & 0xFFFFu);
    }
}

// ---- fp8 gather: rows C bytes, 8 B/lane, unroll-8, HW cvt decode ----------
template <int C>
__global__ __launch_bounds__(256) void gather_f8(const unsigned char* __restrict__ h,
                                                 const int* __restrict__ rowptr,
                                                 const unsigned short* __restrict__ csr,
                                                 unsigned short* __restrict__ agg) {
    const int TPN = C / 8;       // lanes per row (8 B each)
    const int NPB = 256 / TPN;
    int t = threadIdx.x;
    int n = blockIdx.x * NPB + t / TPN;
    if (n >= N_NODES) return;
    int c8 = t % TPN;
    const uint2* hp = (const uint2*)h + c8;
    float acc[8];
#pragma unroll
    for (int j = 0; j < 8; j++) acc[j] = 0.f;
    f8acc(acc, hp[(size_t)n * TPN]);  // self row
    int p = rowptr[n], end = rowptr[n + 1];
    for (; p + 8 <= end; p += 8) {
        int j0 = csr[p],     j1 = csr[p + 1], j2 = csr[p + 2], j3 = csr[p + 3];
        int j4 = csr[p + 4], j5 = csr[p + 5], j6 = csr[p + 6], j7 = csr[p + 7];
        uint2 v0 = hp[(size_t)j0 * TPN];
        uint2 v1 = hp[(size_t)j1 * TPN];
        uint2 v2 = hp[(size_t)j2 * TPN];
        uint2 v3 = hp[(size_t)j3 * TPN];
        uint2 v4 = hp[(size_t)j4 * TPN];
        uint2 v5 = hp[(size_t)j5 * TPN];
        uint2 v6 = hp[(size_t)j6 * TPN];
        uint2 v7 = hp[(size_t)j7 * TPN];
        f8acc(acc, v0); f8acc(acc, v1); f8acc(acc, v2); f8acc(acc, v3);
        f8acc(acc, v4); f8acc(acc, v5); f8acc(acc, v6); f8acc(acc, v7);
    }
    for (; p + 4 <= end; p += 4) {
        int j0 = csr[p], j1 = csr[p + 1], j2 = csr[p + 2], j3 = csr[p + 3];
        uint2 v0 = hp[(size_t)j0 * TPN];
        uint2 v1 = hp[(size_t)j1 * TPN];
        uint2 v2 = hp[(size_t)j2 * TPN];
        uint2 v3 = hp[(size_t)j3 * TPN];
        f8acc(acc, v0); f8acc(acc, v1); f8acc(acc, v2); f8acc(acc, v3);
    }
    for (; p < end; ++p) {
        uint2 v = hp[(size_t)csr[p] * TPN];
        f8acc(acc, v);
    }
    ushort8 o;
#pragma unroll
    for (int j = 0; j < 8; j++) o[j] = f2bf(acc[j]);
    ((ushort8*)agg)[(size_t)n * TPN + c8] = o;  // row = C bf16 = TPN*16 B
}

// ---- MFMA GEMM, BM=64/BN=128 (R6 proven), epilogue type templated ---------
template <int K, int F8OUT>
__global__ __launch_bounds__(256) void gemm_mfma64(
    const unsigned short* __restrict__ A, const unsigned short* __restrict__ W,
    const float* __restrict__ bias, void* __restrict__ Cout, int M) {
    __shared__ short8 As[256];  // 4 KB: 64 A-rows x 32 k
    __shared__ short8 Ws[512];  // 8 KB: 128 W-rows x 32 k

    int tid = threadIdx.x;
    int wave = tid >> 6, lane = tid & 63;
    int wm = wave & 1, wn = wave >> 1;
    int rowbase = blockIdx.x * 64;
    int colbase = blockIdx.y * 128;
    int lkc = lane >> 4, lr = lane & 15;
    int rsw = lr ^ (lkc << 2);
    int rslot = lkc * 16 + rsw;

    int ar = rowbase + wave * 16 + rsw; if (ar >= M) ar = M - 1;
    int wr0 = colbase + (0 * 4 + wave) * 16 + rsw;
    int wr1 = colbase + (1 * 4 + wave) * 16 + rsw;
    char* asb  = (char*)As + (size_t)(wave * 64) * 16;
    char* wsb0 = (char*)Ws + (size_t)(0 * 256 + wave * 64) * 16;
    char* wsb1 = (char*)Ws + (size_t)(1 * 256 + wave * 64) * 16;

    floatx4 acc[2][4];
#pragma unroll
    for (int i = 0; i < 2; i++)
#pragma unroll
        for (int j = 0; j < 4; j++) acc[i][j] = (floatx4)(0.f);

#pragma unroll 2
    for (int k0 = 0; k0 < K; k0 += 32) {
        int ks = k0 + lkc * 8;
        g2lds16(A + (size_t)ar * K + ks, asb);
        g2lds16(W + (size_t)wr0 * K + ks, wsb0);
        g2lds16(W + (size_t)wr1 * K + ks, wsb1);
        __syncthreads();

        short8 af[2], wf[4];
#pragma unroll
        for (int mt = 0; mt < 2; mt++) af[mt] = As[(wm * 2 + mt) * 64 + rslot];
#pragma unroll
        for (int nt = 0; nt < 4; nt++) wf[nt] = Ws[(wn * 4 + nt) * 64 + rslot];
#pragma unroll
        for (int mt = 0; mt < 2; mt++)
#pragma unroll
            for (int nt = 0; nt < 4; nt++)
                acc[mt][nt] = __builtin_amdgcn_mfma_f32_16x16x32_bf16(
                    af[mt], wf[nt], acc[mt][nt], 0, 0, 0);
        __syncthreads();
    }

    // C/D layout: col=lane&15, row=(lane>>4)*4+reg
#pragma unroll
    for (int mt = 0; mt < 2; mt++) {
#pragma unroll
        for (int reg = 0; reg < 4; reg++) {
            int row = rowbase + (wm * 2 + mt) * 16 + lkc * 4 + reg;
            if (row >= M) continue;
#pragma unroll
            for (int nt = 0; nt < 4; nt++) {
                int col = colbase + (wn * 4 + nt) * 16 + lr;
                float v = fmaxf(acc[mt][nt][reg] + bias[col], 0.f);
                if (F8OUT)
                    ((unsigned char*)Cout)[(size_t)row * 256 + col] = ftofp8(v);
                else
                    ((unsigned short*)Cout)[(size_t)row * 256 + col] = f2bf(v);
            }
        }
    }
}

// ------- mean pool, stage 1: streaming accumulate into fp32 sums -----------
__global__ __launch_bounds__(256) void pool_accum(const unsigned short* __restrict__ h,
                                                  const int* __restrict__ batch,
                                                  float* __restrict__ sums) {
    int t = threadIdx.x;  // column 0..255
    int r0 = blockIdx.x * 32;
    int r1 = r0 + 32; if (r1 > N_NODES) r1 = N_NODES;
    if (r0 >= N_NODES) return;
    float acc = 0.f;
    int gcur = batch[r0];
    for (int r = r0; r < r1; ++r) {
        int g = batch[r];
        if (g != gcur) { atomicAdd(&sums[gcur * 256 + t], acc); acc = 0.f; gcur = g; }
        acc += bf2f(h[(size_t)r * 256 + t]);
    }
    atomicAdd(&sums[gcur * 256 + t], acc);
}

// ------- mean pool, stage 2: divide + MLP head (one block per graph) -------
__global__ __launch_bounds__(128) void head(const float* __restrict__ sums,
                                            const int* __restrict__ batch,
                                            const float* __restrict__ Wf1,
                                            const float* __restrict__ bf1,
                                            const float* __restrict__ Wf2,
                                            const float* __restrict__ bf2,
                                            float* __restrict__ out) {
    __shared__ float hg[256];
    __shared__ float hid[128];
    int g = blockIdx.x;
    int t = threadIdx.x;
    int lo = 0, hi = N_NODES;
    while (lo < hi) { int m = (lo + hi) >> 1; if (batch[m] < g) lo = m + 1; else hi = m; }
    int start = lo;
    lo = 0; hi = N_NODES;
    while (lo < hi) { int m = (lo + hi) >> 1; if (batch[m] < g + 1) lo = m + 1; else hi = m; }
    int end = lo;
    float inv = 1.0f / fmaxf((float)(end - start), 1.0f);
    hg[t]       = sums[g * 256 + t] * inv;
    hg[t + 128] = sums[g * 256 + t + 128] * inv;
    __syncthreads();
    float a1 = bf1[t];
    for (int c = 0; c < 256; c++) a1 += hg[c] * Wf1[t * 256 + c];
    hid[t] = fmaxf(a1, 0.f);
    __syncthreads();
    if (t < 10) {
        float a = bf2[t];
        for (int j = 0; j < 128; j++) a += hid[j] * Wf2[t * 128 + j];
        out[g * 10 + t] = a;
    }
}

extern "C" void kernel_launch(void* const* d_in, const int* in_sizes, int n_in,
                              void* d_out, int out_size, void* d_ws, size_t ws_size,
                              hipStream_t stream) {
    const float* x   = (const float*)d_in[0];
    const int*  edge = (const int*)d_in[1];
    const int*  batch= (const int*)d_in[2];
    const float* W1  = (const float*)d_in[3];
    const float* b1  = (const float*)d_in[4];
    const float* W2  = (const float*)d_in[5];
    const float* b2  = (const float*)d_in[6];
    const float* W3  = (const float*)d_in[7];
    const float* b3  = (const float*)d_in[8];
    const float* Wf1 = (const float*)d_in[9];
    const float* bf1 = (const float*)d_in[10];
    const float* Wf2 = (const float*)d_in[11];
    const float* bf2 = (const float*)d_in[12];
    const int* src = edge;
    const int* dst = edge + N_EDGES;

    char* wsb = (char*)d_ws;
    size_t off = 0;
    auto alloc = [&](size_t bytes) { void* p = wsb + off; off += (bytes + 255) & ~(size_t)255; return p; };
    unsigned char*  x_f8   = (unsigned char*)alloc((size_t)N_NODES * 128);
    unsigned char*  h1_f8  = (unsigned char*)alloc((size_t)N_NODES * 256);
    unsigned char*  h2_f8  = (unsigned char*)alloc((size_t)N_NODES * 256);
    unsigned short* agg_bf = (unsigned short*)alloc((size_t)N_NODES * 256 * 2);
    unsigned short* hA_bf  = (unsigned short*)alloc((size_t)N_NODES * 256 * 2);
    unsigned short* W1bf   = (unsigned short*)alloc(256 * 128 * 2);
    unsigned short* W2bf   = (unsigned short*)alloc(256 * 256 * 2);
    unsigned short* W3bf   = (unsigned short*)alloc(256 * 256 * 2);
    int* rowptr    = (int*)alloc((N_NODES + 4) * 4);
    int* cursor    = (int*)alloc(N_NODES * 4);
    int* deg       = (int*)alloc(N_NODES * 4);
    unsigned short* csr = (unsigned short*)alloc((size_t)N_EDGES * 2);
    unsigned int* staging = (unsigned int*)alloc((size_t)N_EDGES * 4);
    int* blocksum  = (int*)alloc(64 * 4);
    int* gcursor   = (int*)alloc(64 * 4);
    float* sums    = (float*)alloc((size_t)N_GRAPHS * 256 * 4);

    const int NB_SCAN = (N_NODES + 1023) / 1024;  // 49

    // ---- prep: memset deg; conv(x->fp8, W->bf16)+hist+zero in one kernel --
    hipMemsetAsync(deg, 0, N_NODES * sizeof(int), stream);
    conv_deg<<<(2473728 + 255) / 256, 256, 0, stream>>>(
        x, W1, W2, W3, dst, x_f8, W1bf, W2bf, W3bf, deg, (float4*)sums);

    // ---- CSR: scan + binned 2-phase scatter (kills write amplification) --
    scan1<<<NB_SCAN, 1024, 0, stream>>>(deg, rowptr, blocksum);
    scan3<<<NB_SCAN, 1024, 0, stream>>>(rowptr, blocksum, cursor, gcursor);
    bin_edges<<<(N_EDGES + 2047) / 2048, 256, 0, stream>>>(src, dst, gcursor, staging);
    scatter_bkt<<<NBKT, 1024, 0, stream>>>(staging, rowptr, cursor, csr);

    dim3 ggrid((N_NODES + 63) / 64, 2);  // 782 x 2 = 1564 blocks

    // ---- layer 1 (K=128): fp8 gather -> bf16 agg -> GEMM -> fp8 h1 ----
    gather_f8<128><<<(N_NODES + 15) / 16, 256, 0, stream>>>(x_f8, rowptr, csr, agg_bf);
    gemm_mfma64<128, 1><<<ggrid, 256, 0, stream>>>(agg_bf, W1bf, b1, h1_f8, N_NODES);

    // ---- layer 2 (K=256) ----
    gather_f8<256><<<(N_NODES + 7) / 8, 256, 0, stream>>>(h1_f8, rowptr, csr, agg_bf);
    gemm_mfma64<256, 1><<<ggrid, 256, 0, stream>>>(agg_bf, W2bf, b2, h2_f8, N_NODES);

    // ---- layer 3 (K=256): bf16 output for the pool ----
    gather_f8<256><<<(N_NODES + 7) / 8, 256, 0, stream>>>(h2_f8, rowptr, csr, agg_bf);
    gemm_mfma64<256, 0><<<ggrid, 256, 0, stream>>>(agg_bf, W3bf, b3, hA_bf, N_NODES);

    // ---- mean pool (sums pre-zeroed in conv_deg) + head ----
    pool_accum<<<(N_NODES + 31) / 32, 256, 0, stream>>>(hA_bf, batch, sums);
    head<<<N_GRAPHS, 128, 0, stream>>>(sums, batch, Wf1, bf1, Wf2, bf2, (float*)d_out);
}

// Round 11
// 319.701 us; speedup vs baseline: 1.2018x; 1.2018x over previous
//
#include <hip/hip_runtime.h>

#define N_NODES 50000
#define N_GRAPHS 512
#define N_EDGES 800000
#define NBKT 49        // ceil(50000/1024) coarse dst-buckets
#define BKT_CAP 20480  // mean 16384, sigma 127 -> 32-sigma headroom

typedef __attribute__((ext_vector_type(8))) short short8;
typedef __attribute__((ext_vector_type(8))) unsigned short ushort8;
typedef __attribute__((ext_vector_type(4))) float floatx4;
typedef __attribute__((ext_vector_type(2))) float floatx2;

__device__ __forceinline__ float bf2f(unsigned short u) {
    union { unsigned int i; float f; } c;
    c.i = ((unsigned int)u) << 16;
    return c.f;
}
__device__ __forceinline__ unsigned short f2bf(float f) {
    union { float f; unsigned int i; } c;
    c.f = f;
    unsigned int u = c.i;
    return (unsigned short)((u + 0x7fffu + ((u >> 16) & 1u)) >> 16);
}

// ---- fp8 e4m3fn encode (software RNE, clamp ±448, flush |v|<2^-6) ---------
// decode is HW v_cvt_pk_f32_fp8 (exact widening, OCP on gfx950).
__device__ __forceinline__ unsigned char ftofp8(float f) {
    union { float f; unsigned int u; } c; c.f = f;
    unsigned int s = (c.u >> 24) & 0x80u;
    float a = fabsf(f);
    if (a < 0x1p-6f) return (unsigned char)s;
    if (a > 448.f)   return (unsigned char)(s | 0x7E);
    unsigned int u = c.u & 0x7FFFFFFFu;
    unsigned int r = u + 0x7FFFFu + ((u >> 20) & 1u);
    return (unsigned char)(s | (((r >> 23) - 120u) << 3) | ((r >> 20) & 7u));
}

// HW decode of 8 packed fp8 (uint2) accumulated into acc[8]
__device__ __forceinline__ void f8acc(float* acc, uint2 v) {
    floatx2 a = __builtin_amdgcn_cvt_pk_f32_fp8(v.x, false);
    floatx2 b = __builtin_amdgcn_cvt_pk_f32_fp8(v.x, true);
    floatx2 c = __builtin_amdgcn_cvt_pk_f32_fp8(v.y, false);
    floatx2 d = __builtin_amdgcn_cvt_pk_f32_fp8(v.y, true);
    acc[0] += a[0]; acc[1] += a[1]; acc[2] += b[0]; acc[3] += b[1];
    acc[4] += c[0]; acc[5] += c[1]; acc[6] += d[0]; acc[7] += d[1];
}

// async 16B global -> LDS (lane-ordered destination: ldsbase + lane*16)
__device__ __forceinline__ void g2lds16(const unsigned short* g, void* lds) {
    __builtin_amdgcn_global_load_lds(
        (const __attribute__((address_space(1))) void*)g,
        (__attribute__((address_space(3))) void*)lds, 16, 0, 0);
}

// ------ fused prep: x->fp8 + W1-3->bf16 + zero sums + zero bktcnt ----------
// R10: the deg histogram fused here (800k cross-XCD atomics) was 43 us with
// 32 MB of dirty-line writes. Removed — the binned CSR build needs no
// global histogram at all with fixed-capacity bucket windows.
// items: [0,1600000) x fp8 | [1600000,1640960) W | [1640960,1673728) sums
//        [1673728,1673792) bktcnt
__global__ void conv_all(const float* __restrict__ x, const float* __restrict__ W1,
                         const float* __restrict__ W2, const float* __restrict__ W3,
                         unsigned char* __restrict__ xf8, unsigned short* __restrict__ o1,
                         unsigned short* __restrict__ o2, unsigned short* __restrict__ o3,
                         float4* __restrict__ sums4, int* __restrict__ bktcnt) {
    int i = blockIdx.x * blockDim.x + threadIdx.x;
    if (i >= 1640960) {
        int j = i - 1640960;
        if (j < 32768) sums4[j] = make_float4(0.f, 0.f, 0.f, 0.f);
        else if (j < 32832) bktcnt[j - 32768] = 0;
        return;
    }
    if (i < 1600000) {
        float4 v = ((const float4*)x)[i];
        uchar4 o;
        o.x = ftofp8(v.x); o.y = ftofp8(v.y); o.z = ftofp8(v.z); o.w = ftofp8(v.w);
        ((uchar4*)xf8)[i] = o;
        return;
    }
    int j = i - 1600000;
    const float* src; unsigned short* out; int base;
    if (j < 8192)       { src = W1; out = o1; base = j; }
    else if (j < 24576) { src = W2; out = o2; base = j - 8192; }
    else                { src = W3; out = o3; base = j - 24576; }
    float4 v = ((const float4*)src)[base];
    ushort4 o;
    o.x = f2bf(v.x); o.y = f2bf(v.y); o.z = f2bf(v.z); o.w = f2bf(v.w);
    ((ushort4*)out)[base] = o;
}

// ---- binned CSR, phase 1: LDS-chunked binning into fixed-cap windows ------
// per block: LDS-count 2048 edges into 49 buckets, reserve chunks with ONE
// global atomic per (block,bucket), write packed (dst:16|src:16) into the
// bucket's private window. Total global atomics: 49x391, not 800k.
__global__ __launch_bounds__(256) void bin_edges(const int* __restrict__ src,
                                                 const int* __restrict__ dst,
                                                 int* __restrict__ bktcnt,
                                                 unsigned int* __restrict__ staging) {
    __shared__ int cnt[NBKT];
    __shared__ int base[NBKT];
    int t = threadIdx.x;
    if (t < NBKT) cnt[t] = 0;
    __syncthreads();
    int e0 = blockIdx.x * 2048;
    int d[8], s[8];
#pragma unroll
    for (int r = 0; r < 8; r++) {
        int e = e0 + r * 256 + t;
        if (e < N_EDGES) {
            d[r] = dst[e]; s[r] = src[e];
            atomicAdd(&cnt[d[r] >> 10], 1);
        } else d[r] = -1;
    }
    __syncthreads();
    if (t < NBKT) base[t] = cnt[t] ? atomicAdd(&bktcnt[t], cnt[t]) : 0;
    __syncthreads();
#pragma unroll
    for (int r = 0; r < 8; r++) {
        if (d[r] >= 0) {
            int bkt = d[r] >> 10;
            int off = atomicAdd(&base[bkt], 1);
            staging[(size_t)bkt * BKT_CAP + off] = ((unsigned)d[r] << 16) | (unsigned)s[r];
        }
    }
}

// ---- binned CSR, phase 2: per-bucket hist + scan + rowptr + scatter -------
// replaces scan1 + scan3 + scatter_bkt. One block per bucket; everything
// (histogram, prefix scan, cursors) lives in LDS; csr writes confined to
// the bucket's ~40 KB window. Bucket bases from a redundant wave-scan.
__global__ __launch_bounds__(1024) void bucket_build(
    const unsigned int* __restrict__ staging, const int* __restrict__ bktcnt,
    int* __restrict__ rowptr, unsigned short* __restrict__ csr) {
    __shared__ int hist[1024];
    __shared__ int s[1024];
    __shared__ int bse[64];
    __shared__ int lcur[1024];
    int b = blockIdx.x, t = threadIdx.x;
    if (t < 64) {
        int orig = (t < NBKT) ? bktcnt[t] : 0;
        int v = orig;
        for (int off = 1; off < 64; off <<= 1) {
            int u = __shfl_up(v, off, 64);
            if (t >= off) v += u;
        }
        bse[t] = v - orig;  // exclusive bucket base
    }
    hist[t] = 0;
    __syncthreads();
    int base = bse[b];
    int cnt = bktcnt[b];
    int n0 = b << 10;
    const unsigned int* stg = staging + (size_t)b * BKT_CAP;
    for (int p = t; p < cnt; p += 1024)
        atomicAdd(&hist[(stg[p] >> 16) - n0], 1);
    __syncthreads();
    int v = hist[t];
    s[t] = v;
    __syncthreads();
    for (int off = 1; off < 1024; off <<= 1) {
        int add = (t >= off) ? s[t - off] : 0;
        __syncthreads();
        s[t] += add;
        __syncthreads();
    }
    int excl = s[t] - v;
    int node = n0 + t;
    if (node < N_NODES) rowptr[node] = base + excl;
    lcur[t] = base + excl;
    if (b == NBKT - 1 && t == 0) rowptr[N_NODES] = N_EDGES;
    __syncthreads();
    for (int p = t; p < cnt; p += 1024) {
        unsigned e = stg[p];
        int li = (int)(e >> 16) - n0;
        int pos = atomicAdd(&lcur[li], 1);
        csr[pos] = (unsigned short)(e & 0xFFFFu);
    }
}

// ---- fp8 gather: rows C bytes, 8 B/lane, unroll-8, HW cvt decode ----------
template <int C>
__global__ __launch_bounds__(256) void gather_f8(const unsigned char* __restrict__ h,
                                                 const int* __restrict__ rowptr,
                                                 const unsigned short* __restrict__ csr,
                                                 unsigned short* __restrict__ agg) {
    const int TPN = C / 8;       // lanes per row (8 B each)
    const int NPB = 256 / TPN;
    int t = threadIdx.x;
    int n = blockIdx.x * NPB + t / TPN;
    if (n >= N_NODES) return;
    int c8 = t % TPN;
    const uint2* hp = (const uint2*)h + c8;
    float acc[8];
#pragma unroll
    for (int j = 0; j < 8; j++) acc[j] = 0.f;
    f8acc(acc, hp[(size_t)n * TPN]);  // self row
    int p = rowptr[n], end = rowptr[n + 1];
    for (; p + 8 <= end; p += 8) {
        int j0 = csr[p],     j1 = csr[p + 1], j2 = csr[p + 2], j3 = csr[p + 3];
        int j4 = csr[p + 4], j5 = csr[p + 5], j6 = csr[p + 6], j7 = csr[p + 7];
        uint2 v0 = hp[(size_t)j0 * TPN];
        uint2 v1 = hp[(size_t)j1 * TPN];
        uint2 v2 = hp[(size_t)j2 * TPN];
        uint2 v3 = hp[(size_t)j3 * TPN];
        uint2 v4 = hp[(size_t)j4 * TPN];
        uint2 v5 = hp[(size_t)j5 * TPN];
        uint2 v6 = hp[(size_t)j6 * TPN];
        uint2 v7 = hp[(size_t)j7 * TPN];
        f8acc(acc, v0); f8acc(acc, v1); f8acc(acc, v2); f8acc(acc, v3);
        f8acc(acc, v4); f8acc(acc, v5); f8acc(acc, v6); f8acc(acc, v7);
    }
    for (; p + 4 <= end; p += 4) {
        int j0 = csr[p], j1 = csr[p + 1], j2 = csr[p + 2], j3 = csr[p + 3];
        uint2 v0 = hp[(size_t)j0 * TPN];
        uint2 v1 = hp[(size_t)j1 * TPN];
        uint2 v2 = hp[(size_t)j2 * TPN];
        uint2 v3 = hp[(size_t)j3 * TPN];
        f8acc(acc, v0); f8acc(acc, v1); f8acc(acc, v2); f8acc(acc, v3);
    }
    for (; p < end; ++p) {
        uint2 v = hp[(size_t)csr[p] * TPN];
        f8acc(acc, v);
    }
    ushort8 o;
#pragma unroll
    for (int j = 0; j < 8; j++) o[j] = f2bf(acc[j]);
    ((ushort8*)agg)[(size_t)n * TPN + c8] = o;  // row = C bf16 = TPN*16 B
}

// ---- MFMA GEMM, BM=64/BN=128 (R6 proven), epilogue type templated ---------
template <int K, int F8OUT>
__global__ __launch_bounds__(256) void gemm_mfma64(
    const unsigned short* __restrict__ A, const unsigned short* __restrict__ W,
    const float* __restrict__ bias, void* __restrict__ Cout, int M) {
    __shared__ short8 As[256];  // 4 KB: 64 A-rows x 32 k
    __shared__ short8 Ws[512];  // 8 KB: 128 W-rows x 32 k

    int tid = threadIdx.x;
    int wave = tid >> 6, lane = tid & 63;
    int wm = wave & 1, wn = wave >> 1;
    int rowbase = blockIdx.x * 64;
    int colbase = blockIdx.y * 128;
    int lkc = lane >> 4, lr = lane & 15;
    int rsw = lr ^ (lkc << 2);
    int rslot = lkc * 16 + rsw;

    int ar = rowbase + wave * 16 + rsw; if (ar >= M) ar = M - 1;
    int wr0 = colbase + (0 * 4 + wave) * 16 + rsw;
    int wr1 = colbase + (1 * 4 + wave) * 16 + rsw;
    char* asb  = (char*)As + (size_t)(wave * 64) * 16;
    char* wsb0 = (char*)Ws + (size_t)(0 * 256 + wave * 64) * 16;
    char* wsb1 = (char*)Ws + (size_t)(1 * 256 + wave * 64) * 16;

    floatx4 acc[2][4];
#pragma unroll
    for (int i = 0; i < 2; i++)
#pragma unroll
        for (int j = 0; j < 4; j++) acc[i][j] = (floatx4)(0.f);

#pragma unroll 2
    for (int k0 = 0; k0 < K; k0 += 32) {
        int ks = k0 + lkc * 8;
        g2lds16(A + (size_t)ar * K + ks, asb);
        g2lds16(W + (size_t)wr0 * K + ks, wsb0);
        g2lds16(W + (size_t)wr1 * K + ks, wsb1);
        __syncthreads();

        short8 af[2], wf[4];
#pragma unroll
        for (int mt = 0; mt < 2; mt++) af[mt] = As[(wm * 2 + mt) * 64 + rslot];
#pragma unroll
        for (int nt = 0; nt < 4; nt++) wf[nt] = Ws[(wn * 4 + nt) * 64 + rslot];
#pragma unroll
        for (int mt = 0; mt < 2; mt++)
#pragma unroll
            for (int nt = 0; nt < 4; nt++)
                acc[mt][nt] = __builtin_amdgcn_mfma_f32_16x16x32_bf16(
                    af[mt], wf[nt], acc[mt][nt], 0, 0, 0);
        __syncthreads();
    }

    // C/D layout: col=lane&15, row=(lane>>4)*4+reg
#pragma unroll
    for (int mt = 0; mt < 2; mt++) {
#pragma unroll
        for (int reg = 0; reg < 4; reg++) {
            int row = rowbase + (wm * 2 + mt) * 16 + lkc * 4 + reg;
            if (row >= M) continue;
#pragma unroll
            for (int nt = 0; nt < 4; nt++) {
                int col = colbase + (wn * 4 + nt) * 16 + lr;
                float v = fmaxf(acc[mt][nt][reg] + bias[col], 0.f);
                if (F8OUT)
                    ((unsigned char*)Cout)[(size_t)row * 256 + col] = ftofp8(v);
                else
                    ((unsigned short*)Cout)[(size_t)row * 256 + col] = f2bf(v);
            }
        }
    }
}

// ------- mean pool, stage 1: streaming accumulate into fp32 sums -----------
__global__ __launch_bounds__(256) void pool_accum(const unsigned short* __restrict__ h,
                                                  const int* __restrict__ batch,
                                                  float* __restrict__ sums) {
    int t = threadIdx.x;  // column 0..255
    int r0 = blockIdx.x * 32;
    int r1 = r0 + 32; if (r1 > N_NODES) r1 = N_NODES;
    if (r0 >= N_NODES) return;
    float acc = 0.f;
    int gcur = batch[r0];
    for (int r = r0; r < r1; ++r) {
        int g = batch[r];
        if (g != gcur) { atomicAdd(&sums[gcur * 256 + t], acc); acc = 0.f; gcur = g; }
        acc += bf2f(h[(size_t)r * 256 + t]);
    }
    atomicAdd(&sums[gcur * 256 + t], acc);
}

// ------- mean pool, stage 2: divide + MLP head (one block per graph) -------
__global__ __launch_bounds__(128) void head(const float* __restrict__ sums,
                                            const int* __restrict__ batch,
                                            const float* __restrict__ Wf1,
                                            const float* __restrict__ bf1,
                                            const float* __restrict__ Wf2,
                                            const float* __restrict__ bf2,
                                            float* __restrict__ out) {
    __shared__ float hg[256];
    __shared__ float hid[128];
    int g = blockIdx.x;
    int t = threadIdx.x;
    int lo = 0, hi = N_NODES;
    while (lo < hi) { int m = (lo + hi) >> 1; if (batch[m] < g) lo = m + 1; else hi = m; }
    int start = lo;
    lo = 0; hi = N_NODES;
    while (lo < hi) { int m = (lo + hi) >> 1; if (batch[m] < g + 1) lo = m + 1; else hi = m; }
    int end = lo;
    float inv = 1.0f / fmaxf((float)(end - start), 1.0f);
    hg[t]       = sums[g * 256 + t] * inv;
    hg[t + 128] = sums[g * 256 + t + 128] * inv;
    __syncthreads();
    float a1 = bf1[t];
    for (int c = 0; c < 256; c++) a1 += hg[c] * Wf1[t * 256 + c];
    hid[t] = fmaxf(a1, 0.f);
    __syncthreads();
    if (t < 10) {
        float a = bf2[t];
        for (int j = 0; j < 128; j++) a += hid[j] * Wf2[t * 128 + j];
        out[g * 10 + t] = a;
    }
}

extern "C" void kernel_launch(void* const* d_in, const int* in_sizes, int n_in,
                              void* d_out, int out_size, void* d_ws, size_t ws_size,
                              hipStream_t stream) {
    const float* x   = (const float*)d_in[0];
    const int*  edge = (const int*)d_in[1];
    const int*  batch= (const int*)d_in[2];
    const float* W1  = (const float*)d_in[3];
    const float* b1  = (const float*)d_in[4];
    const float* W2  = (const float*)d_in[5];
    const float* b2  = (const float*)d_in[6];
    const float* W3  = (const float*)d_in[7];
    const float* b3  = (const float*)d_in[8];
    const float* Wf1 = (const float*)d_in[9];
    const float* bf1 = (const float*)d_in[10];
    const float* Wf2 = (const float*)d_in[11];
    const float* bf2 = (const float*)d_in[12];
    const int* src = edge;
    const int* dst = edge + N_EDGES;

    char* wsb = (char*)d_ws;
    size_t off = 0;
    auto alloc = [&](size_t bytes) { void* p = wsb + off; off += (bytes + 255) & ~(size_t)255; return p; };
    unsigned char*  x_f8   = (unsigned char*)alloc((size_t)N_NODES * 128);
    unsigned char*  h1_f8  = (unsigned char*)alloc((size_t)N_NODES * 256);
    unsigned char*  h2_f8  = (unsigned char*)alloc((size_t)N_NODES * 256);
    unsigned short* agg_bf = (unsigned short*)alloc((size_t)N_NODES * 256 * 2);
    unsigned short* hA_bf  = (unsigned short*)alloc((size_t)N_NODES * 256 * 2);
    unsigned short* W1bf   = (unsigned short*)alloc(256 * 128 * 2);
    unsigned short* W2bf   = (unsigned short*)alloc(256 * 256 * 2);
    unsigned short* W3bf   = (unsigned short*)alloc(256 * 256 * 2);
    int* rowptr    = (int*)alloc((N_NODES + 4) * 4);
    unsigned short* csr = (unsigned short*)alloc((size_t)N_EDGES * 2);
    unsigned int* staging = (unsigned int*)alloc((size_t)NBKT * BKT_CAP * 4);
    int* bktcnt    = (int*)alloc(64 * 4);
    float* sums    = (float*)alloc((size_t)N_GRAPHS * 256 * 4);

    // ---- prep: converts + zeroing (no histogram, no memset) ----
    conv_all<<<(1673792 + 255) / 256, 256, 0, stream>>>(
        x, W1, W2, W3, x_f8, W1bf, W2bf, W3bf, (float4*)sums, bktcnt);

    // ---- CSR: fixed-cap binning + per-bucket build (no scans, no deg) ----
    bin_edges<<<(N_EDGES + 2047) / 2048, 256, 0, stream>>>(src, dst, bktcnt, staging);
    bucket_build<<<NBKT, 1024, 0, stream>>>(staging, bktcnt, rowptr, csr);

    dim3 ggrid((N_NODES + 63) / 64, 2);  // 782 x 2 = 1564 blocks

    // ---- layer 1 (K=128): fp8 gather -> bf16 agg -> GEMM -> fp8 h1 ----
    gather_f8<128><<<(N_NODES + 15) / 16, 256, 0, stream>>>(x_f8, rowptr, csr, agg_bf);
    gemm_mfma64<128, 1><<<ggrid, 256, 0, stream>>>(agg_bf, W1bf, b1, h1_f8, N_NODES);

    // ---- layer 2 (K=256) ----
    gather_f8<256><<<(N_NODES + 7) / 8, 256, 0, stream>>>(h1_f8, rowptr, csr, agg_bf);
    gemm_mfma64<256, 1><<<ggrid, 256, 0, stream>>>(agg_bf, W2bf, b2, h2_f8, N_NODES);

    // ---- layer 3 (K=256): bf16 output for the pool ----
    gather_f8<256><<<(N_NODES + 7) / 8, 256, 0, stream>>>(h2_f8, rowptr, csr, agg_bf);
    gemm_mfma64<256, 0><<<ggrid, 256, 0, stream>>>(agg_bf, W3bf, b3, hA_bf, N_NODES);

    // ---- mean pool (sums pre-zeroed in conv_all) + head ----
    pool_accum<<<(N_NODES + 31) / 32, 256, 0, stream>>>(hA_bf, batch, sums);
    head<<<N_GRAPHS, 128, 0, stream>>>(sums, batch, Wf1, bf1, Wf2, bf2, (float*)d_out);
}

// Round 12
// 314.771 us; speedup vs baseline: 1.2207x; 1.0157x over previous
//
#include <hip/hip_runtime.h>

#define N_NODES 50000
#define N_GRAPHS 512
#define N_EDGES 800000
#define NBKT 49        // ceil(50000/1024) coarse dst-buckets
#define BKT_CAP 20480  // mean 16384, sigma 127 -> 32-sigma headroom

typedef __attribute__((ext_vector_type(8))) short short8;
typedef __attribute__((ext_vector_type(8))) unsigned short ushort8;
typedef __attribute__((ext_vector_type(4))) float floatx4;
typedef __attribute__((ext_vector_type(2))) float floatx2;

__device__ __forceinline__ float bf2f(unsigned short u) {
    union { unsigned int i; float f; } c;
    c.i = ((unsigned int)u) << 16;
    return c.f;
}
__device__ __forceinline__ unsigned short f2bf(float f) {
    union { float f; unsigned int i; } c;
    c.f = f;
    unsigned int u = c.i;
    return (unsigned short)((u + 0x7fffu + ((u >> 16) & 1u)) >> 16);
}

// ---- fp8 e4m3fn encode (software RNE, clamp ±448, flush |v|<2^-6) ---------
// decode is HW v_cvt_pk_f32_fp8 (exact widening, OCP on gfx950).
__device__ __forceinline__ unsigned char ftofp8(float f) {
    union { float f; unsigned int u; } c; c.f = f;
    unsigned int s = (c.u >> 24) & 0x80u;
    float a = fabsf(f);
    if (a < 0x1p-6f) return (unsigned char)s;
    if (a > 448.f)   return (unsigned char)(s | 0x7E);
    unsigned int u = c.u & 0x7FFFFFFFu;
    unsigned int r = u + 0x7FFFFu + ((u >> 20) & 1u);
    return (unsigned char)(s | (((r >> 23) - 120u) << 3) | ((r >> 20) & 7u));
}

// HW decode of 8 packed fp8 (uint2) accumulated into acc[8]
__device__ __forceinline__ void f8acc(float* acc, uint2 v) {
    floatx2 a = __builtin_amdgcn_cvt_pk_f32_fp8(v.x, false);
    floatx2 b = __builtin_amdgcn_cvt_pk_f32_fp8(v.x, true);
    floatx2 c = __builtin_amdgcn_cvt_pk_f32_fp8(v.y, false);
    floatx2 d = __builtin_amdgcn_cvt_pk_f32_fp8(v.y, true);
    acc[0] += a[0]; acc[1] += a[1]; acc[2] += b[0]; acc[3] += b[1];
    acc[4] += c[0]; acc[5] += c[1]; acc[6] += d[0]; acc[7] += d[1];
}

// async 16B global -> LDS (lane-ordered destination: ldsbase + lane*16)
__device__ __forceinline__ void g2lds16(const unsigned short* g, void* lds) {
    __builtin_amdgcn_global_load_lds(
        (const __attribute__((address_space(1))) void*)g,
        (__attribute__((address_space(3))) void*)lds, 16, 0, 0);
}

// ------ FUSED prep: edge binning (blocks [0,391)) + converts/zeroing -------
// R11: conv_all (12 us) and bin_edges (15 us) are independent but a single
// stream serializes them. One kernel, block-range split; bin blocks FIRST
// so they dispatch immediately and run concurrent with the conv stream.
// bktcnt zeroing moved to a 64-int hipMemsetAsync before this kernel.
#define NB_BIN 391   // ceil(800000/2048)
__global__ __launch_bounds__(256) void prep_fused(
    const float* __restrict__ x, const float* __restrict__ W1,
    const float* __restrict__ W2, const float* __restrict__ W3,
    const int* __restrict__ src, const int* __restrict__ dst,
    unsigned char* __restrict__ xf8, unsigned short* __restrict__ o1,
    unsigned short* __restrict__ o2, unsigned short* __restrict__ o3,
    float4* __restrict__ sums4, int* __restrict__ bktcnt,
    unsigned int* __restrict__ staging) {
    int t = threadIdx.x;
    if (blockIdx.x < NB_BIN) {
        // ---- edge binning into fixed-cap bucket windows ----
        __shared__ int cnt[NBKT];
        __shared__ int base[NBKT];
        if (t < NBKT) cnt[t] = 0;
        __syncthreads();
        int e0 = blockIdx.x * 2048;
        int d[8], s[8];
#pragma unroll
        for (int r = 0; r < 8; r++) {
            int e = e0 + r * 256 + t;
            if (e < N_EDGES) {
                d[r] = dst[e]; s[r] = src[e];
                atomicAdd(&cnt[d[r] >> 10], 1);
            } else d[r] = -1;
        }
        __syncthreads();
        if (t < NBKT) base[t] = cnt[t] ? atomicAdd(&bktcnt[t], cnt[t]) : 0;
        __syncthreads();
#pragma unroll
        for (int r = 0; r < 8; r++) {
            if (d[r] >= 0) {
                int bkt = d[r] >> 10;
                int off = atomicAdd(&base[bkt], 1);
                staging[(size_t)bkt * BKT_CAP + off] = ((unsigned)d[r] << 16) | (unsigned)s[r];
            }
        }
        return;
    }
    // ---- converts + zeroing ----
    // items: [0,1600000) x fp8 | [1600000,1640960) W | [1640960,1673728) sums
    int i = (blockIdx.x - NB_BIN) * 256 + t;
    if (i >= 1640960) {
        int j = i - 1640960;
        if (j < 32768) sums4[j] = make_float4(0.f, 0.f, 0.f, 0.f);
        return;
    }
    if (i < 1600000) {
        float4 v = ((const float4*)x)[i];
        uchar4 o;
        o.x = ftofp8(v.x); o.y = ftofp8(v.y); o.z = ftofp8(v.z); o.w = ftofp8(v.w);
        ((uchar4*)xf8)[i] = o;
        return;
    }
    int j = i - 1600000;
    const float* srcp; unsigned short* out; int base;
    if (j < 8192)       { srcp = W1; out = o1; base = j; }
    else if (j < 24576) { srcp = W2; out = o2; base = j - 8192; }
    else                { srcp = W3; out = o3; base = j - 24576; }
    float4 v = ((const float4*)srcp)[base];
    ushort4 o;
    o.x = f2bf(v.x); o.y = f2bf(v.y); o.z = f2bf(v.z); o.w = f2bf(v.w);
    ((ushort4*)out)[base] = o;
}

// ---- binned CSR, phase 2: per-bucket hist + scan + rowptr + scatter -------
__global__ __launch_bounds__(1024) void bucket_build(
    const unsigned int* __restrict__ staging, const int* __restrict__ bktcnt,
    int* __restrict__ rowptr, unsigned short* __restrict__ csr) {
    __shared__ int hist[1024];
    __shared__ int s[1024];
    __shared__ int bse[64];
    __shared__ int lcur[1024];
    int b = blockIdx.x, t = threadIdx.x;
    if (t < 64) {
        int orig = (t < NBKT) ? bktcnt[t] : 0;
        int v = orig;
        for (int off = 1; off < 64; off <<= 1) {
            int u = __shfl_up(v, off, 64);
            if (t >= off) v += u;
        }
        bse[t] = v - orig;  // exclusive bucket base
    }
    hist[t] = 0;
    __syncthreads();
    int base = bse[b];
    int cnt = bktcnt[b];
    int n0 = b << 10;
    const unsigned int* stg = staging + (size_t)b * BKT_CAP;
    for (int p = t; p < cnt; p += 1024)
        atomicAdd(&hist[(stg[p] >> 16) - n0], 1);
    __syncthreads();
    int v = hist[t];
    s[t] = v;
    __syncthreads();
    for (int off = 1; off < 1024; off <<= 1) {
        int add = (t >= off) ? s[t - off] : 0;
        __syncthreads();
        s[t] += add;
        __syncthreads();
    }
    int excl = s[t] - v;
    int node = n0 + t;
    if (node < N_NODES) rowptr[node] = base + excl;
    lcur[t] = base + excl;
    if (b == NBKT - 1 && t == 0) rowptr[N_NODES] = N_EDGES;
    __syncthreads();
    for (int p = t; p < cnt; p += 1024) {
        unsigned e = stg[p];
        int li = (int)(e >> 16) - n0;
        int pos = atomicAdd(&lcur[li], 1);
        csr[pos] = (unsigned short)(e & 0xFFFFu);
    }
}

// ---- fp8 gather: rows C bytes, 8 B/lane, unroll-8, HW cvt decode ----------
template <int C>
__global__ __launch_bounds__(256) void gather_f8(const unsigned char* __restrict__ h,
                                                 const int* __restrict__ rowptr,
                                                 const unsigned short* __restrict__ csr,
                                                 unsigned short* __restrict__ agg) {
    const int TPN = C / 8;       // lanes per row (8 B each)
    const int NPB = 256 / TPN;
    int t = threadIdx.x;
    int n = blockIdx.x * NPB + t / TPN;
    if (n >= N_NODES) return;
    int c8 = t % TPN;
    const uint2* hp = (const uint2*)h + c8;
    float acc[8];
#pragma unroll
    for (int j = 0; j < 8; j++) acc[j] = 0.f;
    f8acc(acc, hp[(size_t)n * TPN]);  // self row
    int p = rowptr[n], end = rowptr[n + 1];
    for (; p + 8 <= end; p += 8) {
        int j0 = csr[p],     j1 = csr[p + 1], j2 = csr[p + 2], j3 = csr[p + 3];
        int j4 = csr[p + 4], j5 = csr[p + 5], j6 = csr[p + 6], j7 = csr[p + 7];
        uint2 v0 = hp[(size_t)j0 * TPN];
        uint2 v1 = hp[(size_t)j1 * TPN];
        uint2 v2 = hp[(size_t)j2 * TPN];
        uint2 v3 = hp[(size_t)j3 * TPN];
        uint2 v4 = hp[(size_t)j4 * TPN];
        uint2 v5 = hp[(size_t)j5 * TPN];
        uint2 v6 = hp[(size_t)j6 * TPN];
        uint2 v7 = hp[(size_t)j7 * TPN];
        f8acc(acc, v0); f8acc(acc, v1); f8acc(acc, v2); f8acc(acc, v3);
        f8acc(acc, v4); f8acc(acc, v5); f8acc(acc, v6); f8acc(acc, v7);
    }
    for (; p + 4 <= end; p += 4) {
        int j0 = csr[p], j1 = csr[p + 1], j2 = csr[p + 2], j3 = csr[p + 3];
        uint2 v0 = hp[(size_t)j0 * TPN];
        uint2 v1 = hp[(size_t)j1 * TPN];
        uint2 v2 = hp[(size_t)j2 * TPN];
        uint2 v3 = hp[(size_t)j3 * TPN];
        f8acc(acc, v0); f8acc(acc, v1); f8acc(acc, v2); f8acc(acc, v3);
    }
    for (; p < end; ++p) {
        uint2 v = hp[(size_t)csr[p] * TPN];
        f8acc(acc, v);
    }
    ushort8 o;
#pragma unroll
    for (int j = 0; j < 8; j++) o[j] = f2bf(acc[j]);
    ((ushort8*)agg)[(size_t)n * TPN + c8] = o;  // row = C bf16 = TPN*16 B
}

// ---- MFMA GEMM, BM=64/BN=128, BK=64 (half the barriers of R6's BK=32) -----
// Per BK=64 round: stage both 32-k halves (6 g2lds calls, 6 in flight)
// then ONE barrier pair covers 16 MFMAs. LDS 24 KB -> still 6 blocks/CU.
template <int K, int F8OUT>
__global__ __launch_bounds__(256) void gemm_mfma64(
    const unsigned short* __restrict__ A, const unsigned short* __restrict__ W,
    const float* __restrict__ bias, void* __restrict__ Cout, int M) {
    __shared__ short8 As[512];   // 8 KB: 2 halves x 64 rows x 32 k
    __shared__ short8 Ws[1024];  // 16 KB: 2 halves x 128 rows x 32 k

    int tid = threadIdx.x;
    int wave = tid >> 6, lane = tid & 63;
    int wm = wave & 1, wn = wave >> 1;
    int rowbase = blockIdx.x * 64;
    int colbase = blockIdx.y * 128;
    int lkc = lane >> 4, lr = lane & 15;
    int rsw = lr ^ (lkc << 2);
    int rslot = lkc * 16 + rsw;

    int ar = rowbase + wave * 16 + rsw; if (ar >= M) ar = M - 1;
    int wr0 = colbase + (0 * 4 + wave) * 16 + rsw;
    int wr1 = colbase + (1 * 4 + wave) * 16 + rsw;
    // LDS bases (16B units): A half h at h*256 + wave*64; W half h at
    // h*512 + i*256 + wave*64.
    char* asb0 = (char*)As + (size_t)(0 * 256 + wave * 64) * 16;
    char* asb1 = (char*)As + (size_t)(1 * 256 + wave * 64) * 16;
    char* wsb00 = (char*)Ws + (size_t)(0 * 512 + 0 * 256 + wave * 64) * 16;
    char* wsb01 = (char*)Ws + (size_t)(0 * 512 + 1 * 256 + wave * 64) * 16;
    char* wsb10 = (char*)Ws + (size_t)(1 * 512 + 0 * 256 + wave * 64) * 16;
    char* wsb11 = (char*)Ws + (size_t)(1 * 512 + 1 * 256 + wave * 64) * 16;

    floatx4 acc[2][4];
#pragma unroll
    for (int i = 0; i < 2; i++)
#pragma unroll
        for (int j = 0; j < 4; j++) acc[i][j] = (floatx4)(0.f);

#pragma unroll 2
    for (int k0 = 0; k0 < K; k0 += 64) {
        int ks0 = k0 + lkc * 8;        // half 0
        int ks1 = k0 + 32 + lkc * 8;   // half 1
        g2lds16(A + (size_t)ar * K + ks0, asb0);
        g2lds16(W + (size_t)wr0 * K + ks0, wsb00);
        g2lds16(W + (size_t)wr1 * K + ks0, wsb01);
        g2lds16(A + (size_t)ar * K + ks1, asb1);
        g2lds16(W + (size_t)wr0 * K + ks1, wsb10);
        g2lds16(W + (size_t)wr1 * K + ks1, wsb11);
        __syncthreads();

#pragma unroll
        for (int h = 0; h < 2; h++) {
            short8 af[2], wf[4];
#pragma unroll
            for (int mt = 0; mt < 2; mt++)
                af[mt] = As[h * 256 + (wm * 2 + mt) * 64 + rslot];
#pragma unroll
            for (int nt = 0; nt < 4; nt++)
                wf[nt] = Ws[h * 512 + (wn * 4 + nt) * 64 + rslot];
#pragma unroll
            for (int mt = 0; mt < 2; mt++)
#pragma unroll
                for (int nt = 0; nt < 4; nt++)
                    acc[mt][nt] = __builtin_amdgcn_mfma_f32_16x16x32_bf16(
                        af[mt], wf[nt], acc[mt][nt], 0, 0, 0);
        }
        __syncthreads();
    }

    // C/D layout: col=lane&15, row=(lane>>4)*4+reg
#pragma unroll
    for (int mt = 0; mt < 2; mt++) {
#pragma unroll
        for (int reg = 0; reg < 4; reg++) {
            int row = rowbase + (wm * 2 + mt) * 16 + lkc * 4 + reg;
            if (row >= M) continue;
#pragma unroll
            for (int nt = 0; nt < 4; nt++) {
                int col = colbase + (wn * 4 + nt) * 16 + lr;
                float v = fmaxf(acc[mt][nt][reg] + bias[col], 0.f);
                if (F8OUT)
                    ((unsigned char*)Cout)[(size_t)row * 256 + col] = ftofp8(v);
                else
                    ((unsigned short*)Cout)[(size_t)row * 256 + col] = f2bf(v);
            }
        }
    }
}

// ------- mean pool, stage 1: streaming accumulate into fp32 sums -----------
__global__ __launch_bounds__(256) void pool_accum(const unsigned short* __restrict__ h,
                                                  const int* __restrict__ batch,
                                                  float* __restrict__ sums) {
    int t = threadIdx.x;  // column 0..255
    int r0 = blockIdx.x * 32;
    int r1 = r0 + 32; if (r1 > N_NODES) r1 = N_NODES;
    if (r0 >= N_NODES) return;
    float acc = 0.f;
    int gcur = batch[r0];
    for (int r = r0; r < r1; ++r) {
        int g = batch[r];
        if (g != gcur) { atomicAdd(&sums[gcur * 256 + t], acc); acc = 0.f; gcur = g; }
        acc += bf2f(h[(size_t)r * 256 + t]);
    }
    atomicAdd(&sums[gcur * 256 + t], acc);
}

// ------- mean pool, stage 2: divide + MLP head (one block per graph) -------
__global__ __launch_bounds__(128) void head(const float* __restrict__ sums,
                                            const int* __restrict__ batch,
                                            const float* __restrict__ Wf1,
                                            const float* __restrict__ bf1,
                                            const float* __restrict__ Wf2,
                                            const float* __restrict__ bf2,
                                            float* __restrict__ out) {
    __shared__ float hg[256];
    __shared__ float hid[128];
    int g = blockIdx.x;
    int t = threadIdx.x;
    int lo = 0, hi = N_NODES;
    while (lo < hi) { int m = (lo + hi) >> 1; if (batch[m] < g) lo = m + 1; else hi = m; }
    int start = lo;
    lo = 0; hi = N_NODES;
    while (lo < hi) { int m = (lo + hi) >> 1; if (batch[m] < g + 1) lo = m + 1; else hi = m; }
    int end = lo;
    float inv = 1.0f / fmaxf((float)(end - start), 1.0f);
    hg[t]       = sums[g * 256 + t] * inv;
    hg[t + 128] = sums[g * 256 + t + 128] * inv;
    __syncthreads();
    float a1 = bf1[t];
    for (int c = 0; c < 256; c++) a1 += hg[c] * Wf1[t * 256 + c];
    hid[t] = fmaxf(a1, 0.f);
    __syncthreads();
    if (t < 10) {
        float a = bf2[t];
        for (int j = 0; j < 128; j++) a += hid[j] * Wf2[t * 128 + j];
        out[g * 10 + t] = a;
    }
}

extern "C" void kernel_launch(void* const* d_in, const int* in_sizes, int n_in,
                              void* d_out, int out_size, void* d_ws, size_t ws_size,
                              hipStream_t stream) {
    const float* x   = (const float*)d_in[0];
    const int*  edge = (const int*)d_in[1];
    const int*  batch= (const int*)d_in[2];
    const float* W1  = (const float*)d_in[3];
    const float* b1  = (const float*)d_in[4];
    const float* W2  = (const float*)d_in[5];
    const float* b2  = (const float*)d_in[6];
    const float* W3  = (const float*)d_in[7];
    const float* b3  = (const float*)d_in[8];
    const float* Wf1 = (const float*)d_in[9];
    const float* bf1 = (const float*)d_in[10];
    const float* Wf2 = (const float*)d_in[11];
    const float* bf2 = (const float*)d_in[12];
    const int* src = edge;
    const int* dst = edge + N_EDGES;

    char* wsb = (char*)d_ws;
    size_t off = 0;
    auto alloc = [&](size_t bytes) { void* p = wsb + off; off += (bytes + 255) & ~(size_t)255; return p; };
    unsigned char*  x_f8   = (unsigned char*)alloc((size_t)N_NODES * 128);
    unsigned char*  h1_f8  = (unsigned char*)alloc((size_t)N_NODES * 256);
    unsigned char*  h2_f8  = (unsigned char*)alloc((size_t)N_NODES * 256);
    unsigned short* agg_bf = (unsigned short*)alloc((size_t)N_NODES * 256 * 2);
    unsigned short* hA_bf  = (unsigned short*)alloc((size_t)N_NODES * 256 * 2);
    unsigned short* W1bf   = (unsigned short*)alloc(256 * 128 * 2);
    unsigned short* W2bf   = (unsigned short*)alloc(256 * 256 * 2);
    unsigned short* W3bf   = (unsigned short*)alloc(256 * 256 * 2);
    int* rowptr    = (int*)alloc((N_NODES + 4) * 4);
    unsigned short* csr = (unsigned short*)alloc((size_t)N_EDGES * 2);
    unsigned int* staging = (unsigned int*)alloc((size_t)NBKT * BKT_CAP * 4);
    int* bktcnt    = (int*)alloc(64 * 4);
    float* sums    = (float*)alloc((size_t)N_GRAPHS * 256 * 4);

    // ---- prep: zero bktcnt; fused binning + converts (overlapped) ----
    hipMemsetAsync(bktcnt, 0, 64 * sizeof(int), stream);
    const int NB_CONV = 1673728 / 256;  // 6538
    prep_fused<<<NB_BIN + NB_CONV, 256, 0, stream>>>(
        x, W1, W2, W3, src, dst, x_f8, W1bf, W2bf, W3bf,
        (float4*)sums, bktcnt, staging);

    // ---- CSR phase 2 ----
    bucket_build<<<NBKT, 1024, 0, stream>>>(staging, bktcnt, rowptr, csr);

    dim3 ggrid((N_NODES + 63) / 64, 2);  // 782 x 2 = 1564 blocks

    // ---- layer 1 (K=128): fp8 gather -> bf16 agg -> GEMM -> fp8 h1 ----
    gather_f8<128><<<(N_NODES + 15) / 16, 256, 0, stream>>>(x_f8, rowptr, csr, agg_bf);
    gemm_mfma64<128, 1><<<ggrid, 256, 0, stream>>>(agg_bf, W1bf, b1, h1_f8, N_NODES);

    // ---- layer 2 (K=256) ----
    gather_f8<256><<<(N_NODES + 7) / 8, 256, 0, stream>>>(h1_f8, rowptr, csr, agg_bf);
    gemm_mfma64<256, 1><<<ggrid, 256, 0, stream>>>(agg_bf, W2bf, b2, h2_f8, N_NODES);

    // ---- layer 3 (K=256): bf16 output for the pool ----
    gather_f8<256><<<(N_NODES + 7) / 8, 256, 0, stream>>>(h2_f8, rowptr, csr, agg_bf);
    gemm_mfma64<256, 0><<<ggrid, 256, 0, stream>>>(agg_bf, W3bf, b3, hA_bf, N_NODES);

    // ---- mean pool (sums pre-zeroed in prep_fused) + head ----
    pool_accum<<<(N_NODES + 31) / 32, 256, 0, stream>>>(hA_bf, batch, sums);
    head<<<N_GRAPHS, 128, 0, stream>>>(sums, batch, Wf1, bf1, Wf2, bf2, (float*)d_out);
}